// Round 1
// baseline (439.877 us; speedup 1.0000x reference)
//
#include <hip/hip_runtime.h>

typedef unsigned short u16;
typedef __attribute__((ext_vector_type(8))) short bf16x8;
typedef __attribute__((ext_vector_type(4))) float f32x4;

__device__ __forceinline__ u16 f2bf(float f) {
  unsigned u = __builtin_bit_cast(unsigned, f);
  u += 0x7fffu + ((u >> 16) & 1u);
  return (u16)(u >> 16);
}

__device__ __forceinline__ void gll16(const void* g, void* l) {
  __builtin_amdgcn_global_load_lds((const __attribute__((address_space(1))) void*)g,
                                   (__attribute__((address_space(3))) void*)l, 16, 0, 0);
}

// ---------------- bias concat: bc[1280] = [bq | bk | bv] ----------------
__global__ void build_bias_k(const float* __restrict__ bq, const float* __restrict__ bk,
                             const float* __restrict__ bv, float* __restrict__ bc) {
  int i = blockIdx.x * 256 + threadIdx.x;
  if (i < 1280) bc[i] = (i < 128) ? bq[i] : ((i < 256) ? bk[i - 128] : bv[i - 256]);
}

// ------- weight transpose: wt[n][f] bf16, n in [0,1280), f in [0,1024) -------
__global__ void transpose_w_k(const float* __restrict__ Wq, const float* __restrict__ Wk,
                              const float* __restrict__ Wv, u16* __restrict__ wt) {
  __shared__ float tile[64][65];
  const int n0 = blockIdx.x * 64;
  const int f0 = blockIdx.y * 64;
  const int t = threadIdx.x;
  const float* src; int ld, coff;
  if (n0 < 128)      { src = Wq; ld = 128;  coff = n0; }
  else if (n0 < 256) { src = Wk; ld = 128;  coff = n0 - 128; }
  else               { src = Wv; ld = 1024; coff = n0 - 256; }
  const int r = t >> 4, c4 = (t & 15) * 4;
  #pragma unroll
  for (int i = 0; i < 4; ++i) {
    float4 v = *(const float4*)(src + (size_t)(f0 + r + 16 * i) * ld + coff + c4);
    tile[r + 16 * i][c4 + 0] = v.x;
    tile[r + 16 * i][c4 + 1] = v.y;
    tile[r + 16 * i][c4 + 2] = v.z;
    tile[r + 16 * i][c4 + 3] = v.w;
  }
  __syncthreads();
  #pragma unroll
  for (int i = 0; i < 4; ++i) {
    const int nr = r + 16 * i;
    ushort4 h;
    h.x = f2bf(tile[c4 + 0][nr]);
    h.y = f2bf(tile[c4 + 1][nr]);
    h.z = f2bf(tile[c4 + 2][nr]);
    h.w = f2bf(tile[c4 + 3][nr]);
    *(ushort4*)(wt + (size_t)(n0 + nr) * 1024 + f0 + c4) = h;
  }
}

// ---------------- fused QKV GEMM: [32768,1024] @ [1024,1280] + bias ----------------
// q,k (cols 0..255) -> qkv[m][256] bf16 ; v (cols 256..1279) -> vt[bg][h][s] bf16 (transposed)
__global__ __launch_bounds__(256, 2) void gemm_qkv_k(
    const float* __restrict__ x, const u16* __restrict__ wt,
    const float* __restrict__ bc, u16* __restrict__ qkv, u16* __restrict__ vt) {
  __shared__ u16 sA[128 * 64];
  __shared__ u16 sB[128 * 64];
  char* sAc = (char*)sA;
  char* sBc = (char*)sB;
  const int t = threadIdx.x;
  const int w = t >> 6, lane = t & 63;
  const int wr = w >> 1, wc = w & 1;
  const int lm = lane & 15, lg = lane >> 4;
  const int m0 = blockIdx.x * 128;
  const f32x4 FZ = {0.f, 0.f, 0.f, 0.f};

  // A staging: thread covers 8 x (16B fp32 load -> 8B bf16 LDS write), rows t/16 + 16i
  const int arow = t >> 4;
  const float* xb = x + (size_t)(m0 + arow) * 1024 + (t & 15) * 4;
  const int aswz = ((t >> 4) & 7) << 4;        // XOR swizzle (row&7)<<4
  // B staging via global_load_lds with pre-swizzled source
  const int brow = t >> 3;
  const int bcol = 8 * ((t & 7) ^ ((t >> 3) & 7));
  const int kswz = (lm & 7) << 4;              // read-side swizzle (row%8 == lm%8)

  for (int nt = blockIdx.y * 5; nt < blockIdx.y * 5 + 5; ++nt) {
    const int n0 = nt * 128;
    f32x4 acc[4][4];
    #pragma unroll
    for (int mi = 0; mi < 4; ++mi)
      #pragma unroll
      for (int ni = 0; ni < 4; ++ni) acc[mi][ni] = FZ;
    const u16* wb = wt + (size_t)(n0 + brow) * 1024 + bcol;
    for (int kt = 0; kt < 16; ++kt) {
      const int k0 = kt * 64;
      #pragma unroll
      for (int i = 0; i < 8; ++i) {
        float4 v = *(const float4*)(xb + (size_t)(16 * i) * 1024 + k0);
        ushort4 h;
        h.x = f2bf(v.x); h.y = f2bf(v.y); h.z = f2bf(v.z); h.w = f2bf(v.w);
        *(ushort4*)(sAc + (((t + 256 * i) * 8) ^ aswz)) = h;
      }
      #pragma unroll
      for (int i = 0; i < 4; ++i)
        gll16(wb + (size_t)(32 * i) * 1024 + k0, sBc + w * 1024 + 4096 * i);
      __syncthreads();
      #pragma unroll
      for (int ks = 0; ks < 2; ++ks) {
        const int ka = (ks * 64 + lg * 16) ^ kswz;
        bf16x8 aF[4], bF[4];
        #pragma unroll
        for (int mi = 0; mi < 4; ++mi)
          aF[mi] = *(const bf16x8*)(sAc + (wr * 64 + mi * 16 + lm) * 128 + ka);
        #pragma unroll
        for (int ni = 0; ni < 4; ++ni)
          bF[ni] = *(const bf16x8*)(sBc + (wc * 64 + ni * 16 + lm) * 128 + ka);
        #pragma unroll
        for (int mi = 0; mi < 4; ++mi)
          #pragma unroll
          for (int ni = 0; ni < 4; ++ni)
            acc[mi][ni] = __builtin_amdgcn_mfma_f32_16x16x32_bf16(aF[mi], bF[ni], acc[mi][ni], 0, 0, 0);
      }
      __syncthreads();
    }
    // epilogue: bias + store (C/D layout: col = lane&15, row = (lane>>4)*4 + j)
    #pragma unroll
    for (int ni = 0; ni < 4; ++ni) {
      const int col = n0 + wc * 64 + ni * 16 + lm;
      const float bias = bc[col];
      if (n0 < 256) {
        #pragma unroll
        for (int mi = 0; mi < 4; ++mi) {
          const int r0 = m0 + wr * 64 + mi * 16 + lg * 4;
          #pragma unroll
          for (int j = 0; j < 4; ++j)
            qkv[(size_t)(r0 + j) * 256 + col] = f2bf(acc[mi][ni][j] + bias);
        }
      } else {
        const int h = col - 256;
        #pragma unroll
        for (int mi = 0; mi < 4; ++mi) {
          const int r0 = m0 + wr * 64 + mi * 16 + lg * 4;
          const int bg = r0 >> 10;
          const int sb = r0 & 1023;
          ushort4 pk;
          pk.x = f2bf(acc[mi][ni][0] + bias);
          pk.y = f2bf(acc[mi][ni][1] + bias);
          pk.z = f2bf(acc[mi][ni][2] + bias);
          pk.w = f2bf(acc[mi][ni][3] + bias);
          *(ushort4*)(vt + ((size_t)(bg * 1024 + h) << 10) + sb) = pk;
        }
      }
    }
  }
}

// ---------------- flash attention + epilogue (gamma*O/l + x) ----------------
// grid (qt=16, bg=32), 512 threads = 8 waves: wave = (qw = w>>1 owns 16 q rows, hw = w&1 owns 512 h cols)
__global__ __launch_bounds__(512, 2) void attn_k(
    const u16* __restrict__ qk, const u16* __restrict__ vt,
    const float* __restrict__ x, const float* __restrict__ gam,
    float* __restrict__ out) {
  __shared__ u16 sK[32 * 128];     // K tile, XOR-swizzled rows (256B each)
  __shared__ u16 sV[1024 * 32];    // V^T tile [h][kv], 64B rows (bank-uniform reads)
  __shared__ u16 sP[8 * 16 * 32];  // per-wave P buffer [16 q][32 kv]
  char* sKc = (char*)sK;
  char* sVc = (char*)sV;
  char* sPc = (char*)sP;
  const int t = threadIdx.x;
  const int w = t >> 6, lane = t & 63;
  const int qw = w >> 1, hw = w & 1;
  const int lm = lane & 15, lg = lane >> 4;
  const int qt = blockIdx.x, bg = blockIdx.y;
  const f32x4 FZ = {0.f, 0.f, 0.f, 0.f};

  // Q fragments hoisted (A operand: row = lane&15, k = 8*(lane>>4)+i)
  const int qrow = bg * 1024 + qt * 64 + qw * 16 + lm;
  bf16x8 qf[4];
  #pragma unroll
  for (int ks = 0; ks < 4; ++ks)
    qf[ks] = *(const bf16x8*)(qk + (size_t)qrow * 256 + ks * 32 + lg * 8);

  f32x4 oacc[32];
  #pragma unroll
  for (int ni = 0; ni < 32; ++ni) oacc[ni] = FZ;
  float m_run[4], l_run[4];
  #pragma unroll
  for (int j = 0; j < 4; ++j) { m_run[j] = -3e38f; l_run[j] = 0.f; }

  const char* qkc = (const char*)qk;
  const char* vtc = (const char*)vt;
  const int krow = t >> 4;                                   // 0..31
  const int kcolx = ((t & 15) * 16) ^ ((krow & 7) << 4);     // pre-swizzled source col
  const char* ksrc = qkc + (size_t)(bg * 1024 + krow) * 512 + 256 + kcolx;

  for (int kv0 = 0; kv0 < 1024; kv0 += 32) {
    __syncthreads();  // previous iteration done reading LDS
    gll16(ksrc + (size_t)kv0 * 512, sKc + w * 1024);
    #pragma unroll
    for (int i = 0; i < 8; ++i) {
      const int c = t + 512 * i;
      gll16(vtc + (size_t)(bg * 1024 + (c >> 2)) * 2048 + kv0 * 2 + (c & 3) * 16,
            sVc + w * 1024 + 8192 * i);
    }
    __syncthreads();  // staged tiles visible (vmcnt drained by barrier)

    // S = Q @ K^T  (two 16-col chunks)
    f32x4 sc0 = FZ, sc1 = FZ;
    const int sw = (lm & 7) << 4;
    #pragma unroll
    for (int ks = 0; ks < 4; ++ks) {
      bf16x8 kf = *(const bf16x8*)(sKc + lm * 256 + ((ks * 64 + lg * 16) ^ sw));
      sc0 = __builtin_amdgcn_mfma_f32_16x16x32_bf16(qf[ks], kf, sc0, 0, 0, 0);
    }
    #pragma unroll
    for (int ks = 0; ks < 4; ++ks) {
      bf16x8 kf = *(const bf16x8*)(sKc + (16 + lm) * 256 + ((ks * 64 + lg * 16) ^ sw));
      sc1 = __builtin_amdgcn_mfma_f32_16x16x32_bf16(qf[ks], kf, sc1, 0, 0, 0);
    }

    // online softmax (rows = lg*4+j; reduce across the 16 lanes of same lg group)
    float mx[4];
    #pragma unroll
    for (int j = 0; j < 4; ++j) mx[j] = fmaxf(sc0[j], sc1[j]);
    #pragma unroll
    for (int d = 1; d < 16; d <<= 1)
      #pragma unroll
      for (int j = 0; j < 4; ++j) mx[j] = fmaxf(mx[j], __shfl_xor(mx[j], d));
    int grow = 0;
    #pragma unroll
    for (int j = 0; j < 4; ++j) grow |= (mx[j] > m_run[j] + 8.0f) ? 1 : 0;
    if (__any(grow)) {  // defer-max: only rescale when max grew past threshold
      #pragma unroll
      for (int j = 0; j < 4; ++j) {
        const float mi_ = fmaxf(m_run[j], mx[j]);
        const float al = __expf(m_run[j] - mi_);
        m_run[j] = mi_;
        l_run[j] *= al;
        #pragma unroll
        for (int ni = 0; ni < 32; ++ni) oacc[ni][j] *= al;
      }
    }
    float p0[4], p1[4], rs[4];
    #pragma unroll
    for (int j = 0; j < 4; ++j) {
      p0[j] = __expf(sc0[j] - m_run[j]);
      p1[j] = __expf(sc1[j] - m_run[j]);
      rs[j] = p0[j] + p1[j];
    }
    #pragma unroll
    for (int d = 1; d < 16; d <<= 1)
      #pragma unroll
      for (int j = 0; j < 4; ++j) rs[j] += __shfl_xor(rs[j], d);
    #pragma unroll
    for (int j = 0; j < 4; ++j) l_run[j] += rs[j];

    // P -> per-wave LDS buffer (D layout in, A layout out)
    #pragma unroll
    for (int j = 0; j < 4; ++j) {
      char* pb = sPc + w * 1024 + (lg * 4 + j) * 64;
      *(u16*)(pb + lm * 2) = f2bf(p0[j]);
      *(u16*)(pb + (lm + 16) * 2) = f2bf(p1[j]);
    }
    __syncthreads();  // P visible (also keeps sV alive until PV done)

    bf16x8 pa = *(const bf16x8*)(sPc + w * 1024 + lm * 64 + lg * 16);
    #pragma unroll
    for (int ni = 0; ni < 32; ++ni) {
      bf16x8 vf = *(const bf16x8*)(sVc + (hw * 512 + ni * 16 + lm) * 64 + lg * 16);
      oacc[ni] = __builtin_amdgcn_mfma_f32_16x16x32_bf16(pa, vf, oacc[ni], 0, 0, 0);
    }
  }

  // epilogue: out = gamma * O/l + x
  const float g0 = gam[0];
  #pragma unroll
  for (int j = 0; j < 4; ++j) {
    const float inv = 1.0f / l_run[j];
    const size_t ro = (size_t)(bg * 1024 + qt * 64 + qw * 16 + lg * 4 + j) * 1024;
    #pragma unroll
    for (int ni = 0; ni < 32; ++ni) {
      const int col = hw * 512 + ni * 16 + lm;
      out[ro + col] = g0 * oacc[ni][j] * inv + x[ro + col];
    }
  }
}

extern "C" void kernel_launch(void* const* d_in, const int* in_sizes, int n_in,
                              void* d_out, int out_size, void* d_ws, size_t ws_size,
                              hipStream_t stream) {
  const float* x  = (const float*)d_in[0];
  const float* Wq = (const float*)d_in[1];
  const float* bq = (const float*)d_in[2];
  const float* Wk = (const float*)d_in[3];
  const float* bk = (const float*)d_in[4];
  const float* Wv = (const float*)d_in[5];
  const float* bv = (const float*)d_in[6];
  const float* gm = (const float*)d_in[7];
  float* out = (float*)d_out;

  char* ws = (char*)d_ws;
  u16*   wt = (u16*)(ws);                 // 1280*1024*2       = 2,621,440 B
  float* bc = (float*)(ws + 2621440);     // 1280*4            = 5,120 B
  u16*   qk = (u16*)(ws + 2626560);       // 32768*256*2       = 16,777,216 B
  u16*   vt = (u16*)(ws + 19403776);      // 32*1024*1024*2    = 67,108,864 B  (total ~86.5 MB)

  build_bias_k<<<5, 256, 0, stream>>>(bq, bk, bv, bc);
  transpose_w_k<<<dim3(20, 16), 256, 0, stream>>>(Wq, Wk, Wv, wt);
  gemm_qkv_k<<<dim3(256, 2), 256, 0, stream>>>(x, wt, bc, qk, vt);
  attn_k<<<dim3(16, 32), 512, 0, stream>>>(qk, vt, x, gm, out);
}